// Round 1
// baseline (735.300 us; speedup 1.0000x reference)
//
#include <hip/hip_runtime.h>
#include <stdint.h>

typedef short bf16x8 __attribute__((ext_vector_type(8)));
typedef float f32x4 __attribute__((ext_vector_type(4)));

#define NEG (-10000.0f)
constexpr int T_LEN = 512;
constexpr int BATCH = 128;

__device__ __forceinline__ unsigned short f2bf(float f) {
    union { float f; unsigned u; } v; v.f = f;
    return (unsigned short)((v.u + 0x7FFFu + ((v.u >> 16) & 1u)) >> 16);
}

// ---------------- 1) embedding gather + bf16 convert: xt[b][t][64] ----------------
__global__ void __launch_bounds__(256) k_embed(const int* __restrict__ sent,
                                               const float* __restrict__ emb,
                                               unsigned short* __restrict__ xt) {
    int gid = blockIdx.x * 256 + threadIdx.x;      // 65536*32 threads
    int row = gid >> 5;                            // b*T + t
    int p   = gid & 31;                            // float2 pair within the 64-wide row
    int w = sent[row];
    float2 v = *(const float2*)(emb + (size_t)w * 64 + p * 2);
    unsigned o = (unsigned)f2bf(v.x) | ((unsigned)f2bf(v.y) << 16);
    ((unsigned*)xt)[(size_t)row * 32 + p] = o;
}

// ---------------- 2) BiLSTM recurrence: one (batch,dir) chain per block ----------------
// block: 256 threads = 4 waves; wave w computes gate w (z dims [128w,128w+128))
// Weights live in registers as MFMA B-fragments. A operand = broadcast s=[x|h] (all 16
// M-rows identical), so every lane's acc[..][0] holds z[16*nt + (lane&15)].
__global__ void __launch_bounds__(256, 1) k_lstm(
        const unsigned short* __restrict__ xt,     // (B,T,64) bf16
        const float* __restrict__ Wih_f, const float* __restrict__ Whh_f, const float* __restrict__ b_f,
        const float* __restrict__ Wih_b, const float* __restrict__ Whh_b, const float* __restrict__ b_b,
        unsigned short* __restrict__ hbuf) {       // (B,T,256) bf16: [h_f | h_b]
    const int tid  = threadIdx.x;
    const int lane = tid & 63;
    const int w    = tid >> 6;            // wave id == gate id (i,f,g,o)
    const int b    = blockIdx.x & 127;
    const int dir  = blockIdx.x >> 7;

    const float* Wih  = dir ? Wih_b : Wih_f;
    const float* Whh  = dir ? Whh_b : Whh_f;
    const float* bias = dir ? b_b   : b_f;

    __shared__ __align__(16) unsigned short sbuf[192];  // [x(64) | h(128)] bf16
    __shared__ float zbuf[512];
    __shared__ float sbias[512];

    sbias[tid]       = bias[tid];
    sbias[tid + 256] = bias[tid + 256];

    const int nlo = lane & 15;            // n within 16-tile
    const int kg  = lane >> 4;            // k-group 0..3 (8 k each)

    // ---- preload B fragments: 6 k-tiles (x:0-1, h:2-5) x 8 n-tiles ----
    bf16x8 bfrag[6][8];
    #pragma unroll
    for (int ntl = 0; ntl < 8; ++ntl) {
        int j = 128 * w + 16 * ntl + nlo;            // gate-output row
        #pragma unroll
        for (int kt = 0; kt < 6; ++kt) {
            const float* src = (kt < 2) ? (Wih + (size_t)j * 64  + 32 * kt       + kg * 8)
                                        : (Whh + (size_t)j * 128 + 32 * (kt - 2) + kg * 8);
            bf16x8 tmp;
            #pragma unroll
            for (int q = 0; q < 8; ++q) tmp[q] = (short)f2bf(src[q]);
            bfrag[kt][ntl] = tmp;
        }
    }

    // ---- init: h=0, load x(t0) ----
    if (tid >= 64 && tid < 192) sbuf[tid] = 0;       // h part = sbuf[64..192)
    {
        int t0 = dir ? (T_LEN - 1) : 0;
        if (tid < 8)
            ((uint4*)sbuf)[tid] = ((const uint4*)(xt + ((size_t)b * T_LEN + t0) * 64))[tid];
    }
    float c = 0.0f;                                   // valid for tid < 128
    __syncthreads();

    for (int step = 0; step < T_LEN; ++step) {
        const int t_src = dir ? (T_LEN - 1 - step) : step;

        // prefetch next x row into registers (wave 2, lanes 0-7)
        uint4 xpre;
        const bool do_pre = (w == 2) && (lane < 8) && (step + 1 < T_LEN);
        if (do_pre) {
            int t_nxt = dir ? (t_src - 1) : (t_src + 1);
            xpre = ((const uint4*)(xt + ((size_t)b * T_LEN + t_nxt) * 64))[lane];
        }

        // ---- MFMA phase: z = [x|h] . W^T ----
        f32x4 acc[8];
        #pragma unroll
        for (int ntl = 0; ntl < 8; ++ntl) acc[ntl] = (f32x4){0.f, 0.f, 0.f, 0.f};
        #pragma unroll
        for (int kt = 0; kt < 6; ++kt) {
            bf16x8 a = *(const bf16x8*)(sbuf + 32 * kt + kg * 8);   // broadcast s k-slice
            #pragma unroll
            for (int ntl = 0; ntl < 8; ++ntl)
                acc[ntl] = __builtin_amdgcn_mfma_f32_16x16x32_bf16(a, bfrag[kt][ntl], acc[ntl], 0, 0, 0);
        }
        if (lane < 16) {
            #pragma unroll
            for (int ntl = 0; ntl < 8; ++ntl)
                zbuf[128 * w + 16 * ntl + lane] = acc[ntl][0];
        }
        __syncthreads();

        // ---- gate phase: threads 0..127 own hidden unit u=tid ----
        if (tid < 128) {
            float zi = zbuf[tid]       + sbias[tid];
            float zf = zbuf[128 + tid] + sbias[128 + tid];
            float zg = zbuf[256 + tid] + sbias[256 + tid];
            float zo = zbuf[384 + tid] + sbias[384 + tid];
            float ig = 1.0f / (1.0f + __expf(-zi));
            float fg = 1.0f / (1.0f + __expf(-zf));
            float gg = 2.0f / (1.0f + __expf(-2.0f * zg)) - 1.0f;
            float og = 1.0f / (1.0f + __expf(-zo));
            c = fg * c + ig * gg;
            float h = og * (2.0f / (1.0f + __expf(-2.0f * c)) - 1.0f);
            unsigned short hb = f2bf(h);
            sbuf[64 + tid] = hb;
            hbuf[((size_t)b * T_LEN + t_src) * 256 + dir * 128 + tid] = hb;
        }
        if (do_pre) ((uint4*)sbuf)[lane] = xpre;      // write next x into sbuf[0..64)
        __syncthreads();
    }
}

// ---------------- 3) feats = [h_f|h_b] @ W_out^T + b_out  (BT x 32) ----------------
__global__ void __launch_bounds__(256) k_feats(const unsigned short* __restrict__ hbuf,
                                               const float* __restrict__ Wout,
                                               const float* __restrict__ bout,
                                               float* __restrict__ feats) {
    const int lane = threadIdx.x & 63;
    const int wv   = blockIdx.x * 4 + (threadIdx.x >> 6);  // 0..1023, 64 rows each
    const int nlo  = lane & 15, kg = lane >> 4;

    bf16x8 bw[2][8];
    #pragma unroll
    for (int nt = 0; nt < 2; ++nt) {
        const float* src0 = Wout + (size_t)(nt * 16 + nlo) * 256 + kg * 8;
        #pragma unroll
        for (int kt = 0; kt < 8; ++kt) {
            bf16x8 tmp;
            #pragma unroll
            for (int q = 0; q < 8; ++q) tmp[q] = (short)f2bf(src0[kt * 32 + q]);
            bw[nt][kt] = tmp;
        }
    }
    float bb0 = bout[nlo], bb1 = bout[16 + nlo];

    for (int rg = 0; rg < 4; ++rg) {
        int row0 = wv * 64 + rg * 16;
        f32x4 a0 = {0.f,0.f,0.f,0.f}, a1 = {0.f,0.f,0.f,0.f};
        #pragma unroll
        for (int kt = 0; kt < 8; ++kt) {
            bf16x8 a = *(const bf16x8*)(hbuf + (size_t)(row0 + nlo) * 256 + kt * 32 + kg * 8);
            a0 = __builtin_amdgcn_mfma_f32_16x16x32_bf16(a, bw[0][kt], a0, 0, 0, 0);
            a1 = __builtin_amdgcn_mfma_f32_16x16x32_bf16(a, bw[1][kt], a1, 0, 0, 0);
        }
        #pragma unroll
        for (int r = 0; r < 4; ++r) {
            size_t rr = (size_t)(row0 + kg * 4 + r) * 32;
            feats[rr + nlo]      = a0[r] + bb0;
            feats[rr + 16 + nlo] = a1[r] + bb1;
        }
    }
}

// ---------------- 4) CRF forward + gold, one wave per batch ----------------
__global__ void __launch_bounds__(64) k_crf(const float* __restrict__ feats,
                                            const float* __restrict__ trans,
                                            const int* __restrict__ tags,
                                            float* __restrict__ out) {
    const int b    = blockIdx.x;
    const int lane = threadIdx.x;
    const int k1   = lane & 31;
    const int half = lane >> 5;

    __shared__ __align__(16) float fv[32];
    __shared__ float str[1024];

    for (int i = lane; i < 1024; i += 64) str[i] = trans[i];
    float tr[16];
    #pragma unroll
    for (int j = 0; j < 16; ++j) tr[j] = trans[k1 * 32 + half * 16 + j];
    if (lane < 32) fv[lane] = (lane == 0) ? 0.0f : NEG;
    __syncthreads();

    // gold score (parallel over t, then wave-reduce)
    const int* tg = tags + (size_t)b * T_LEN;
    const float* fb = feats + (size_t)b * T_LEN * 32;
    float gsum = 0.0f;
    for (int t = lane; t < T_LEN; t += 64) {
        int cur = tg[t];
        int prev = t ? tg[t - 1] : 0;
        gsum += str[cur * 32 + prev] + fb[(size_t)t * 32 + cur];
    }
    #pragma unroll
    for (int o = 32; o >= 1; o >>= 1) gsum += __shfl_xor(gsum, o);

    // forward algorithm
    float ev = fb[k1];
    for (int t = 0; t < T_LEN; ++t) {
        float evn = (t + 1 < T_LEN) ? fb[(size_t)(t + 1) * 32 + k1] : 0.0f;
        float fvv[16];
        #pragma unroll
        for (int j = 0; j < 16; j += 4) {
            float4 q = *(const float4*)(fv + half * 16 + j);
            fvv[j] = q.x; fvv[j + 1] = q.y; fvv[j + 2] = q.z; fvv[j + 3] = q.w;
        }
        float s[16];
        #pragma unroll
        for (int j = 0; j < 16; ++j) s[j] = fvv[j] + tr[j];
        float m = s[0];
        #pragma unroll
        for (int j = 1; j < 16; ++j) m = fmaxf(m, s[j]);
        m = fmaxf(m, __shfl_xor(m, 32));
        float sum = 0.0f;
        #pragma unroll
        for (int j = 0; j < 16; ++j) sum += __expf(s[j] - m);
        sum += __shfl_xor(sum, 32);
        float lse = m + __logf(sum);
        __syncthreads();
        if (half == 0) fv[k1] = lse + ev;
        __syncthreads();
        ev = evn;
    }

    // logZ = lse_k(fv[k] + trans[0][k])
    float v = (lane < 32) ? (fv[lane] + str[lane]) : -3.0e38f;
    float m2 = v;
    #pragma unroll
    for (int o = 32; o >= 1; o >>= 1) m2 = fmaxf(m2, __shfl_xor(m2, o));
    float e = (lane < 32) ? __expf(v - m2) : 0.0f;
    #pragma unroll
    for (int o = 32; o >= 1; o >>= 1) e += __shfl_xor(e, o);
    float logZ = m2 + __logf(e);

    if (lane == 0) {
        float gold = gsum + str[tg[T_LEN - 1]];   // + trans[0][last]
        atomicAdd(out, logZ - gold);
    }
}

extern "C" void kernel_launch(void* const* d_in, const int* in_sizes, int n_in,
                              void* d_out, int out_size, void* d_ws, size_t ws_size,
                              hipStream_t stream) {
    const int*   sent  = (const int*)d_in[0];
    const int*   tags  = (const int*)d_in[1];
    const float* emb   = (const float*)d_in[2];
    const float* Wih_f = (const float*)d_in[3];
    const float* Whh_f = (const float*)d_in[4];
    const float* b_f   = (const float*)d_in[5];
    const float* Wih_b = (const float*)d_in[6];
    const float* Whh_b = (const float*)d_in[7];
    const float* b_b   = (const float*)d_in[8];
    const float* Wout  = (const float*)d_in[9];
    const float* bout  = (const float*)d_in[10];
    const float* trans = (const float*)d_in[11];
    (void)in_sizes; (void)n_in; (void)ws_size;

    char* ws = (char*)d_ws;
    unsigned short* hbuf = (unsigned short*)ws;                          // 33,554,432 B
    float*          feats = (float*)(ws + 33554432);                     //  8,388,608 B
    unsigned short* xt    = (unsigned short*)(ws + 33554432 + 8388608);  //  8,388,608 B

    hipMemsetAsync(d_out, 0, sizeof(float) * out_size, stream);
    k_embed<<<8192, 256, 0, stream>>>(sent, emb, xt);
    k_lstm <<<256,  256, 0, stream>>>(xt, Wih_f, Whh_f, b_f, Wih_b, Whh_b, b_b, hbuf);
    k_feats<<<256,  256, 0, stream>>>(hbuf, Wout, bout, feats);
    k_crf  <<<BATCH, 64, 0, stream>>>(feats, trans, tags, (float*)d_out);
}

// Round 4
// 635.450 us; speedup vs baseline: 1.1571x; 1.1571x over previous
//
#include <hip/hip_runtime.h>
#include <stdint.h>

typedef short bf16x8 __attribute__((ext_vector_type(8)));
typedef float f32x4 __attribute__((ext_vector_type(4)));

#define NEG (-10000.0f)
#define LOG2E 1.44269504089f
#define LN2 0.69314718056f
#define EXP2F(x) __builtin_amdgcn_exp2f(x)
#define LOG2F(x) __builtin_amdgcn_logf(x)
constexpr int T_LEN = 512;
constexpr int BATCH = 128;

__device__ __forceinline__ unsigned short f2bf(float f) {
    union { float f; unsigned u; } v; v.f = f;
    return (unsigned short)((v.u + 0x7FFFu + ((v.u >> 16) & 1u)) >> 16);
}

__device__ __forceinline__ f32x4 mfma16(bf16x8 a, bf16x8 b, f32x4 c) {
    return __builtin_amdgcn_mfma_f32_16x16x32_bf16(a, b, c, 0, 0, 0);
}

// ---------------- 1) embedding gather + bf16 convert: xt[b][t][64] ----------------
__global__ void __launch_bounds__(256) k_embed(const int* __restrict__ sent,
                                               const float* __restrict__ emb,
                                               unsigned short* __restrict__ xt) {
    int gid = blockIdx.x * 256 + threadIdx.x;
    int row = gid >> 5;                            // b*T + t
    int p   = gid & 31;
    int w = sent[row];
    float2 v = *(const float2*)(emb + (size_t)w * 64 + p * 2);
    unsigned o = (unsigned)f2bf(v.x) | ((unsigned)f2bf(v.y) << 16);
    ((unsigned*)xt)[(size_t)row * 32 + p] = o;
}

// ---------------- 2) BiLSTM: one (batch,dir) chain per block, 8 waves ----------------
// Wave w owns hidden units [16w,16w+16): computes z for ALL 4 gates of those units,
// so gate math is in-register (no cross-wave z exchange). h ping-pong in LDS; one raw
// barrier per step (lgkmcnt-only wait — the hbuf global store never drains in-loop).
__global__ void __launch_bounds__(512, 2) k_lstm(
        const unsigned short* __restrict__ xt,     // (B,T,64) bf16
        const float* __restrict__ Wih_f, const float* __restrict__ Whh_f, const float* __restrict__ b_f,
        const float* __restrict__ Wih_b, const float* __restrict__ Whh_b, const float* __restrict__ b_b,
        unsigned short* __restrict__ hbuf) {       // (B,T,256) bf16: [h_f | h_b]
    const int tid  = threadIdx.x;
    const int lane = tid & 63;
    const int w    = tid >> 6;            // wave 0..7: unit slice [16w,16w+16)
    const int b    = blockIdx.x & 127;
    const int dir  = blockIdx.x >> 7;

    const float* Wih  = dir ? Wih_b : Wih_f;
    const float* Whh  = dir ? Whh_b : Whh_f;
    const float* bias = dir ? b_b   : b_f;

    __shared__ __align__(16) unsigned short xl[T_LEN * 64];   // 64 KB: whole x sequence
    __shared__ __align__(16) unsigned short hl[2][128];       // h ping-pong

    const int nlo = lane & 15;
    const int kg  = lane >> 4;
    const int u   = 16 * w + nlo;         // hidden unit owned by this lane

    // ---- B fragments: 6 k-tiles x 4 gates, weights resident in VGPRs ----
    bf16x8 bfrag[6][4];
    float bs[4];
    #pragma unroll
    for (int g = 0; g < 4; ++g) {
        int j = 128 * g + u;
        bs[g] = bias[j];
        #pragma unroll
        for (int kt = 0; kt < 6; ++kt) {
            const float* src = (kt < 2) ? (Wih + (size_t)j * 64  + 32 * kt       + kg * 8)
                                        : (Whh + (size_t)j * 128 + 32 * (kt - 2) + kg * 8);
            bf16x8 tmp;
            #pragma unroll
            for (int q = 0; q < 8; ++q) tmp[q] = (short)f2bf(src[q]);
            bfrag[kt][g] = tmp;
        }
    }

    // ---- stage whole x sequence into LDS; zero h ----
    {
        const uint4* xs = (const uint4*)(xt + (size_t)b * T_LEN * 64);
        for (int i = tid; i < T_LEN * 64 / 8; i += 512) ((uint4*)xl)[i] = xs[i];
    }
    if (tid < 128) { hl[0][tid] = 0; hl[1][tid] = 0; }
    __syncthreads();

    float c = 0.0f;                        // cell state (kg-redundant, lockstep)
    const size_t hb_base = ((size_t)b * T_LEN) * 256 + (size_t)dir * 128 + u;

    const int t0 = dir ? (T_LEN - 1) : 0;
    bf16x8 ax0 = *(const bf16x8*)(xl + t0 * 64      + kg * 8);
    bf16x8 ax1 = *(const bf16x8*)(xl + t0 * 64 + 32 + kg * 8);

    for (int step = 0; step < T_LEN; ++step) {
        const int t_src = dir ? (T_LEN - 1 - step) : step;
        const int p = step & 1;

        const unsigned short* hr = hl[p];
        bf16x8 a2 = *(const bf16x8*)(hr      + kg * 8);
        bf16x8 a3 = *(const bf16x8*)(hr + 32 + kg * 8);
        bf16x8 a4 = *(const bf16x8*)(hr + 64 + kg * 8);
        bf16x8 a5 = *(const bf16x8*)(hr + 96 + kg * 8);

        f32x4 acc[4];
        #pragma unroll
        for (int g = 0; g < 4; ++g) {
            f32x4 a = (f32x4){0.f, 0.f, 0.f, 0.f};
            a = mfma16(ax0, bfrag[0][g], a);
            a = mfma16(ax1, bfrag[1][g], a);
            a = mfma16(a2,  bfrag[2][g], a);
            a = mfma16(a3,  bfrag[3][g], a);
            a = mfma16(a4,  bfrag[4][g], a);
            a = mfma16(a5,  bfrag[5][g], a);
            acc[g] = a;
        }

        // prefetch next step's x slices during gate math (xl is read-only)
        if (step + 1 < T_LEN) {
            const int tn = dir ? (t_src - 1) : (t_src + 1);
            ax0 = *(const bf16x8*)(xl + tn * 64      + kg * 8);
            ax1 = *(const bf16x8*)(xl + tn * 64 + 32 + kg * 8);
        }

        float zi = acc[0][0] + bs[0];
        float zf = acc[1][0] + bs[1];
        float zg = acc[2][0] + bs[2];
        float zo = acc[3][0] + bs[3];
        float ig = 1.0f / (1.0f + __expf(-zi));
        float fg = 1.0f / (1.0f + __expf(-zf));
        float gg = 2.0f / (1.0f + __expf(-2.0f * zg)) - 1.0f;
        float og = 1.0f / (1.0f + __expf(-zo));
        c = fg * c + ig * gg;
        float hh = og * (2.0f / (1.0f + __expf(-2.0f * c)) - 1.0f);
        unsigned short hv = f2bf(hh);

        if (kg == 0) {
            hl[1 - p][u] = hv;                              // next step's A operand
            hbuf[hb_base + (size_t)t_src * 256] = hv;       // fire-and-forget
        }

        // raw barrier: wait LDS ops only (lgkmcnt(0) = 0xc07f), NOT the global store
        __asm__ volatile("" ::: "memory");
        __builtin_amdgcn_s_waitcnt(0xc07f);
        __builtin_amdgcn_s_barrier();
        __asm__ volatile("" ::: "memory");
    }
}

// ---------------- 3) feats = [h_f|h_b] @ W_out^T + b_out  (BT x 32) ----------------
__global__ void __launch_bounds__(256) k_feats(const unsigned short* __restrict__ hbuf,
                                               const float* __restrict__ Wout,
                                               const float* __restrict__ bout,
                                               float* __restrict__ feats) {
    const int lane = threadIdx.x & 63;
    const int wv   = blockIdx.x * 4 + (threadIdx.x >> 6);
    const int nlo  = lane & 15, kg = lane >> 4;

    bf16x8 bw[2][8];
    #pragma unroll
    for (int nt = 0; nt < 2; ++nt) {
        const float* src0 = Wout + (size_t)(nt * 16 + nlo) * 256 + kg * 8;
        #pragma unroll
        for (int kt = 0; kt < 8; ++kt) {
            bf16x8 tmp;
            #pragma unroll
            for (int q = 0; q < 8; ++q) tmp[q] = (short)f2bf(src0[kt * 32 + q]);
            bw[nt][kt] = tmp;
        }
    }
    float bb0 = bout[nlo], bb1 = bout[16 + nlo];

    for (int rg = 0; rg < 4; ++rg) {
        int row0 = wv * 64 + rg * 16;
        f32x4 a0 = {0.f,0.f,0.f,0.f}, a1 = {0.f,0.f,0.f,0.f};
        #pragma unroll
        for (int kt = 0; kt < 8; ++kt) {
            bf16x8 a = *(const bf16x8*)(hbuf + (size_t)(row0 + nlo) * 256 + kt * 32 + kg * 8);
            a0 = mfma16(a, bw[0][kt], a0);
            a1 = mfma16(a, bw[1][kt], a1);
        }
        #pragma unroll
        for (int r = 0; r < 4; ++r) {
            size_t rr = (size_t)(row0 + kg * 4 + r) * 32;
            feats[rr + nlo]      = a0[r] + bb0;
            feats[rr + 16 + nlo] = a1[r] + bb1;
        }
    }
}

// ---------------- 4) CRF forward + gold: one wave per batch, fv in registers ----------------
// log2-domain, stale COMMON offset (lane 16's previous fv — the bulk level L).
// Exact for any offset while exp2 args are in range; regular lanes sit within ~±10
// of L. Lane k=0 (trans row 0 = NEG) underflows p→0; clamp to 1e-37 pins fv[0]
// ~123 below L instead of ~14427 — provably identical downstream (re-enters only
// through another −14427, underflowing to 0 contribution either way).
__global__ void __launch_bounds__(64) k_crf(const float* __restrict__ feats,
                                            const float* __restrict__ trans,
                                            const int* __restrict__ tags,
                                            float* __restrict__ out) {
    const int b    = blockIdx.x;
    const int lane = threadIdx.x;
    const int k1   = lane & 31;
    const int half = lane >> 5;

    __shared__ float str[1024];
    for (int i = lane; i < 1024; i += 64) str[i] = trans[i];

    float tr2[16];
    #pragma unroll
    for (int j = 0; j < 16; ++j) tr2[j] = trans[k1 * 32 + half * 16 + j] * LOG2E;
    __syncthreads();

    // gold score
    const int* tg = tags + (size_t)b * T_LEN;
    const float* fb = feats + (size_t)b * T_LEN * 32;
    float gsum = 0.0f;
    for (int t = lane; t < T_LEN; t += 64) {
        int cur = tg[t];
        int prev = t ? tg[t - 1] : 0;
        gsum += str[cur * 32 + prev] + fb[(size_t)t * 32 + cur];
    }
    #pragma unroll
    for (int o = 32; o >= 1; o >>= 1) gsum += __shfl_xor(gsum, o);

    // forward recurrence (log2 domain, register fv, shuffle gather)
    float fv2  = (k1 == 0) ? 0.0f : NEG * LOG2E;
    float coff = NEG * LOG2E;              // common stale offset (bulk level)
    float ev2  = fb[k1] * LOG2E;

    for (int t = 0; t < T_LEN; ++t) {
        float evn = (t + 1 < T_LEN) ? fb[(size_t)(t + 1) * 32 + k1] : 0.0f;
        float trc[16];
        #pragma unroll
        for (int j = 0; j < 16; ++j) trc[j] = tr2[j] - coff;
        float p0 = 0.f, p1 = 0.f, p2 = 0.f, p3 = 0.f;
        #pragma unroll
        for (int j = 0; j < 16; j += 4) {
            float f0 = __shfl(fv2, half * 16 + j);
            float f1 = __shfl(fv2, half * 16 + j + 1);
            float f2 = __shfl(fv2, half * 16 + j + 2);
            float f3 = __shfl(fv2, half * 16 + j + 3);
            p0 += EXP2F(f0 + trc[j]);
            p1 += EXP2F(f1 + trc[j + 1]);
            p2 += EXP2F(f2 + trc[j + 2]);
            p3 += EXP2F(f3 + trc[j + 3]);
        }
        float p = (p0 + p1) + (p2 + p3);
        p += __shfl_xor(p, 32);
        p = fmaxf(p, 1e-37f);              // lane-0 underflow guard (see header)
        fv2  = coff + LOG2F(p) + ev2;
        coff = __shfl(fv2, 16);            // new common offset: bulk lane's level
        ev2  = evn * LOG2E;
    }

    // logZ = ln2 * lse2_k(fv2 + trans[0][k]*log2e); butterfly over 64 (dups => /2)
    float v2 = fv2 + str[k1] * LOG2E;
    float m2 = v2;
    #pragma unroll
    for (int o = 32; o >= 1; o >>= 1) m2 = fmaxf(m2, __shfl_xor(m2, o));
    float e = EXP2F(v2 - m2);
    #pragma unroll
    for (int o = 32; o >= 1; o >>= 1) e += __shfl_xor(e, o);
    float logZ = LN2 * (m2 + LOG2F(e) - 1.0f);   // -1: each k counted twice

    if (lane == 0) {
        float gold = gsum + str[tg[T_LEN - 1]];
        atomicAdd(out, logZ - gold);
    }
}

extern "C" void kernel_launch(void* const* d_in, const int* in_sizes, int n_in,
                              void* d_out, int out_size, void* d_ws, size_t ws_size,
                              hipStream_t stream) {
    const int*   sent  = (const int*)d_in[0];
    const int*   tags  = (const int*)d_in[1];
    const float* emb   = (const float*)d_in[2];
    const float* Wih_f = (const float*)d_in[3];
    const float* Whh_f = (const float*)d_in[4];
    const float* b_f   = (const float*)d_in[5];
    const float* Wih_b = (const float*)d_in[6];
    const float* Whh_b = (const float*)d_in[7];
    const float* b_b   = (const float*)d_in[8];
    const float* Wout  = (const float*)d_in[9];
    const float* bout  = (const float*)d_in[10];
    const float* trans = (const float*)d_in[11];
    (void)in_sizes; (void)n_in; (void)ws_size;

    char* ws = (char*)d_ws;
    unsigned short* hbuf  = (unsigned short*)ws;                         // 33,554,432 B
    float*          feats = (float*)(ws + 33554432);                     //  8,388,608 B
    unsigned short* xt    = (unsigned short*)(ws + 33554432 + 8388608);  //  8,388,608 B

    (void)hipMemsetAsync(d_out, 0, sizeof(float) * out_size, stream);
    k_embed<<<8192, 256, 0, stream>>>(sent, emb, xt);
    k_lstm <<<256,  512, 0, stream>>>(xt, Wih_f, Whh_f, b_f, Wih_b, Whh_b, b_b, hbuf);
    k_feats<<<256,  256, 0, stream>>>(hbuf, Wout, bout, feats);
    k_crf  <<<BATCH, 64, 0, stream>>>(feats, trans, tags, (float*)d_out);
}